// Round 20
// baseline (119.979 us; speedup 1.0000x reference)
//
#include <hip/hip_runtime.h>
#include <math.h>
#include <stdint.h>

#define B_   4
#define N_   2048
#define D_   512
#define DK_  512
#define NH_  8
#define HK_  64
#define LN_EPS_ 1e-5f
// softmax runs in exp2 domain: Q is pre-scaled by 1/sqrt(64) * log2(e)
#define QS_  0.18033688011112042f

typedef unsigned short u16;
typedef __attribute__((ext_vector_type(8))) short short8;
typedef __attribute__((ext_vector_type(4))) float f32x4;
typedef __attribute__((ext_vector_type(8))) unsigned short u16x8;

__device__ __forceinline__ u16 f2bf(float x) {          // RNE
    uint32_t u = __builtin_bit_cast(uint32_t, x);
    return (u16)((u + 0x7fffu + ((u >> 16) & 1u)) >> 16);
}
__device__ __forceinline__ u16 f2bf_fast(float x) {     // round-half-up (2 ops)
    return (u16)((__builtin_bit_cast(uint32_t, x) + 0x8000u) >> 16);
}
__device__ __forceinline__ float b2f(u16 v) {
    return __builtin_bit_cast(float, (uint32_t)v << 16);
}
// HW packed bf16 convert: lo -> bits[15:0], hi -> bits[31:16] (T12 recipe)
__device__ __forceinline__ uint32_t cvtpk_bf16(float lo, float hi) {
    uint32_t r;
    asm("v_cvt_pk_bf16_f32 %0, %1, %2" : "=v"(r) : "v"(lo), "v"(hi));
    return r;
}
__device__ __forceinline__ float exp2f_fast(float x) {
    return __builtin_amdgcn_exp2f(x);
}

// async global->LDS, 16B/lane; LDS dest = wave-uniform base + lane*16
__device__ __forceinline__ void gload16(const void* g, void* l) {
    __builtin_amdgcn_global_load_lds(
        reinterpret_cast<const __attribute__((address_space(1))) void*>(
            reinterpret_cast<uintptr_t>(g)),
        reinterpret_cast<__attribute__((address_space(3))) void*>(
            static_cast<uint32_t>(reinterpret_cast<uintptr_t>(l))),
        16, 0, 0);
}

// ---------------------------------------------------------------------------
// Prep: tc3 only (Wq/Wk/Wv transpose -> wqkvT), 768 blocks.
// (x-conv folded into QKV staging; tcf rides the fat kernel.)
// ---------------------------------------------------------------------------
__global__ __launch_bounds__(256) void prep_kernel(
    const float* __restrict__ Wq, const float* __restrict__ Wk,
    const float* __restrict__ Wv, u16* __restrict__ wqkvT)
{
    __shared__ float t[32][33];
    const int bid = blockIdx.x, tid = threadIdx.x;
    const int z = bid >> 8, rem = bid & 255;
    const float* W = z == 0 ? Wq : (z == 1 ? Wk : Wv);
    u16* dst = wqkvT + (size_t)z * 512 * 512;
    const int nt = (rem & 15) * 32, kt = (rem >> 4) * 32;
    {
        const int r = tid >> 3, c0 = (tid & 7) * 4;
        const float4 v = *reinterpret_cast<const float4*>(
            &W[(size_t)(kt + r) * 512 + nt + c0]);
        t[r][c0] = v.x; t[r][c0 + 1] = v.y; t[r][c0 + 2] = v.z; t[r][c0 + 3] = v.w;
    }
    __syncthreads();
    {
        const int nidx = tid >> 3, kc = (tid & 7) * 4;
        u16 o[4];
        #pragma unroll
        for (int j = 0; j < 4; ++j) o[j] = f2bf(t[kc + j][nidx]);
        *reinterpret_cast<ushort4*>(&dst[(size_t)(nt + nidx) * 512 + kt + kc]) =
            make_ushort4(o[0], o[1], o[2], o[3]);
    }
}

// ---------------------------------------------------------------------------
// QKV GEMM: x fp32 [8192,512] @ wqkvT[1536,512]^T -> q/k/v. 64x128 tile,
// BK=64, 2-phase static dbuf. A-staging reads x fp32 directly: loads issued
// early to registers (T14), converted (RNE, identical to old prep) and
// ds_written with the same XOR-swizzled LDS image AFTER the compute phase.
// Split epilogue: q pre-scaled by QS_, v dual-written to vb + vt.
// ---------------------------------------------------------------------------
__global__ __launch_bounds__(256) void gemm_qkv_kernel(
    const float* __restrict__ X, const u16* __restrict__ Bt,
    u16* __restrict__ qb, u16* __restrict__ kb,
    u16* __restrict__ vb, u16* __restrict__ vt)
{
    __shared__ u16 As0[64 * 64], As1[64 * 64];
    __shared__ u16 Bs0[128 * 64], Bs1[128 * 64];
    const int tid = threadIdx.x;
    const int lane = tid & 63, wave = tid >> 6;
    const int wm = wave >> 1, wn = wave & 1;
    const int l15 = lane & 15, lg = lane >> 4;
    const int bid = ((int)blockIdx.x & 7) * 192 + ((int)blockIdx.x >> 3);
    const int nt = (bid % 12) * 128;         // 1536/128 = 12 n-tiles
    const int mt = (bid / 12) * 64;

    // A-staging geometry: thread covers row ar_, 16 cols from ac0_
    const int ar_ = tid >> 2;
    const int ac0_ = (tid & 3) * 16;
    const int aswz_ = (ar_ & 7) << 4;
    float4 al0, al1, al2, al3;

    f32x4 acc[2][4] = {};

#define A_LOAD(kt) do {                                                        \
    const float* xp_ = &X[(size_t)(mt + ar_) * 512 + (kt) * 64 + ac0_];        \
    al0 = *reinterpret_cast<const float4*>(xp_);                               \
    al1 = *reinterpret_cast<const float4*>(xp_ + 4);                           \
    al2 = *reinterpret_cast<const float4*>(xp_ + 8);                           \
    al3 = *reinterpret_cast<const float4*>(xp_ + 12);                          \
} while (0)

#define A_WRITE(AS) do {                                                       \
    u16x8 w0_, w1_;                                                            \
    w0_[0] = f2bf(al0.x); w0_[1] = f2bf(al0.y);                                \
    w0_[2] = f2bf(al0.z); w0_[3] = f2bf(al0.w);                                \
    w0_[4] = f2bf(al1.x); w0_[5] = f2bf(al1.y);                                \
    w0_[6] = f2bf(al1.z); w0_[7] = f2bf(al1.w);                                \
    w1_[0] = f2bf(al2.x); w1_[1] = f2bf(al2.y);                                \
    w1_[2] = f2bf(al2.z); w1_[3] = f2bf(al2.w);                                \
    w1_[4] = f2bf(al3.x); w1_[5] = f2bf(al3.y);                                \
    w1_[6] = f2bf(al3.z); w1_[7] = f2bf(al3.w);                                \
    *reinterpret_cast<u16x8*>((char*)(AS) + ar_ * 128 +                        \
                              ((2 * ac0_) ^ aswz_)) = w0_;                     \
    *reinterpret_cast<u16x8*>((char*)(AS) + ar_ * 128 +                        \
                              ((2 * ac0_ + 16) ^ aswz_)) = w1_;                \
} while (0)

#define B_STAGE(kt, BS) do {                                                   \
    _Pragma("unroll")                                                          \
    for (int i_ = 0; i_ < 4; ++i_) {                                           \
        const int ob_ = (wave * 4 + i_) * 1024;                                \
        const int o_ = ob_ + lane * 16;                                        \
        const int row_ = o_ >> 7;                                              \
        const int inner_ = (o_ & 127) ^ ((row_ & 7) << 4);                     \
        gload16((const char*)Bt + ((size_t)(nt + row_) * 512 + (kt) * 64) * 2  \
                    + inner_, (char*)(BS) + ob_);                              \
    }                                                                          \
} while (0)

#define QKV_COMP(AS, BS) do {                                                  \
    _Pragma("unroll")                                                          \
    for (int ks = 0; ks < 2; ++ks) {                                           \
        const int kb2 = ks * 32 + lg * 8;                                      \
        short8 af[2], bfr[4];                                                  \
        _Pragma("unroll")                                                      \
        for (int mi = 0; mi < 2; ++mi) {                                       \
            const int r = wm * 32 + mi * 16 + l15;                             \
            af[mi] = *reinterpret_cast<const short8*>(                         \
                &(AS)[r * 64 + (kb2 ^ ((r & 7) << 3))]);                       \
        }                                                                      \
        _Pragma("unroll")                                                      \
        for (int ni = 0; ni < 4; ++ni) {                                       \
            const int r = wn * 64 + ni * 16 + l15;                             \
            bfr[ni] = *reinterpret_cast<const short8*>(                        \
                &(BS)[r * 64 + (kb2 ^ ((r & 7) << 3))]);                       \
        }                                                                      \
        _Pragma("unroll")                                                      \
        for (int mi = 0; mi < 2; ++mi)                                         \
            _Pragma("unroll")                                                  \
            for (int ni = 0; ni < 4; ++ni)                                     \
                acc[mi][ni] = __builtin_amdgcn_mfma_f32_16x16x32_bf16(         \
                    af[mi], bfr[ni], acc[mi][ni], 0, 0, 0);                    \
    }                                                                          \
} while (0)

    A_LOAD(0); B_STAGE(0, Bs0); A_WRITE(As0);
    __syncthreads();
    #pragma unroll 1
    for (int kt = 0; kt < 8; kt += 2) {
        A_LOAD(kt + 1); B_STAGE(kt + 1, Bs1);
        QKV_COMP(As0, Bs0);
        A_WRITE(As1);
        __syncthreads();
        if (kt + 2 < 8) { A_LOAD(kt + 2); B_STAGE(kt + 2, Bs0); }
        QKV_COMP(As1, Bs1);
        if (kt + 2 < 8) A_WRITE(As0);
        __syncthreads();
    }
#undef A_LOAD
#undef A_WRITE
#undef B_STAGE
#undef QKV_COMP

    #pragma unroll
    for (int mi = 0; mi < 2; ++mi) {
        #pragma unroll
        for (int ni = 0; ni < 4; ++ni) {
            const int col = nt + wn * 64 + ni * 16 + l15;
            const int row0 = mt + wm * 32 + mi * 16 + lg * 4;
            if (col < 512) {
                #pragma unroll
                for (int jj = 0; jj < 4; ++jj)
                    qb[(size_t)(row0 + jj) * 512 + col] =
                        f2bf(acc[mi][ni][jj] * QS_);
            } else if (col < 1024) {
                #pragma unroll
                for (int jj = 0; jj < 4; ++jj)
                    kb[(size_t)(row0 + jj) * 512 + col - 512] =
                        f2bf(acc[mi][ni][jj]);
            } else {
                const int dfull = col - 1024;
                const int hh = dfull >> 6, dd = dfull & 63;
                const int bb = row0 >> 11, nn = row0 & 2047;
                u16 o4[4];
                #pragma unroll
                for (int jj = 0; jj < 4; ++jj) {
                    o4[jj] = f2bf(acc[mi][ni][jj]);
                    vb[(size_t)(row0 + jj) * 512 + dfull] = o4[jj];
                }
                *reinterpret_cast<ushort4*>(
                    &vt[(((size_t)(bb * NH_ + hh)) * HK_ + dd) * N_ + nn]) =
                    make_ushort4(o4[0], o4[1], o4[2], o4[3]);
            }
        }
    }
}

// ---------------------------------------------------------------------------
// FC GEMM: [8192,1024] @ wfT[512,1024]^T -> bf16 [8192,512], 64x128 tile,
// BK=64, 2-phase static double-buffer. bias + relu + resid epilogue.
// ---------------------------------------------------------------------------
__global__ __launch_bounds__(256) void gemm_fc_kernel(
    const u16* __restrict__ A, const u16* __restrict__ Bt,
    u16* __restrict__ C, const float* __restrict__ bias,
    const float* __restrict__ resid)
{
    __shared__ u16 As0[64 * 64], As1[64 * 64];
    __shared__ u16 Bs0[128 * 64], Bs1[128 * 64];
    const int tid = threadIdx.x;
    const int lane = tid & 63, wave = tid >> 6;
    const int wm = wave >> 1, wn = wave & 1;
    const int l15 = lane & 15, lg = lane >> 4;
    const int bid = ((int)blockIdx.x & 7) * 64 + ((int)blockIdx.x >> 3);
    const int nt = (bid & 3) * 128;          // 512/128 = 4 n-tiles
    const int mt = (bid >> 2) * 64;

    f32x4 acc[2][4] = {};

#define FC_STAGE(kt, AS, BS) do {                                              \
    _Pragma("unroll")                                                          \
    for (int i_ = 0; i_ < 2; ++i_) {                                           \
        const int ob_ = (wave * 2 + i_) * 1024;                                \
        const int o_ = ob_ + lane * 16;                                        \
        const int row_ = o_ >> 7;                                              \
        const int inner_ = (o_ & 127) ^ ((row_ & 7) << 4);                     \
        gload16((const char*)A + ((size_t)(mt + row_) * 1024 + (kt) * 64) * 2  \
                    + inner_, (char*)(AS) + ob_);                              \
    }                                                                          \
    _Pragma("unroll")                                                          \
    for (int i_ = 0; i_ < 4; ++i_) {                                           \
        const int ob_ = (wave * 4 + i_) * 1024;                                \
        const int o_ = ob_ + lane * 16;                                        \
        const int row_ = o_ >> 7;                                              \
        const int inner_ = (o_ & 127) ^ ((row_ & 7) << 4);                     \
        gload16((const char*)Bt + ((size_t)(nt + row_) * 1024 + (kt) * 64) * 2 \
                    + inner_, (char*)(BS) + ob_);                              \
    }                                                                          \
} while (0)

#define FC_COMP(AS, BS) do {                                                   \
    _Pragma("unroll")                                                          \
    for (int ks = 0; ks < 2; ++ks) {                                           \
        const int kb2 = ks * 32 + lg * 8;                                      \
        short8 af[2], bfr[4];                                                  \
        _Pragma("unroll")                                                      \
        for (int mi = 0; mi < 2; ++mi) {                                       \
            const int r = wm * 32 + mi * 16 + l15;                             \
            af[mi] = *reinterpret_cast<const short8*>(                         \
                &(AS)[r * 64 + (kb2 ^ ((r & 7) << 3))]);                       \
        }                                                                      \
        _Pragma("unroll")                                                      \
        for (int ni = 0; ni < 4; ++ni) {                                       \
            const int r = wn * 64 + ni * 16 + l15;                             \
            bfr[ni] = *reinterpret_cast<const short8*>(                        \
                &(BS)[r * 64 + (kb2 ^ ((r & 7) << 3))]);                       \
        }                                                                      \
        _Pragma("unroll")                                                      \
        for (int mi = 0; mi < 2; ++mi)                                         \
            _Pragma("unroll")                                                  \
            for (int ni = 0; ni < 4; ++ni)                                     \
                acc[mi][ni] = __builtin_amdgcn_mfma_f32_16x16x32_bf16(         \
                    af[mi], bfr[ni], acc[mi][ni], 0, 0, 0);                    \
    }                                                                          \
} while (0)

    FC_STAGE(0, As0, Bs0);
    __syncthreads();
    #pragma unroll 1
    for (int kt = 0; kt < 16; kt += 2) {
        FC_STAGE(kt + 1, As1, Bs1);         // kt+1 <= 15 always
        FC_COMP(As0, Bs0);
        __syncthreads();
        if (kt + 2 < 16) FC_STAGE(kt + 2, As0, Bs0);
        FC_COMP(As1, Bs1);
        __syncthreads();
    }
#undef FC_STAGE
#undef FC_COMP

    #pragma unroll
    for (int mi = 0; mi < 2; ++mi) {
        #pragma unroll
        for (int ni = 0; ni < 4; ++ni) {
            const int col = nt + wn * 64 + ni * 16 + l15;
            const int row0 = mt + wm * 32 + mi * 16 + lg * 4;
            #pragma unroll
            for (int jj = 0; jj < 4; ++jj) {
                const size_t row = (size_t)(row0 + jj);
                float v = acc[mi][ni][jj];
                v += bias[col];
                v = fmaxf(v, 0.0f);
                v += resid[row * 512 + col];
                C[row * 512 + col] = f2bf(v);
            }
        }
    }
}

// ---------------------------------------------------------------------------
// FAT kernel: [0,512) = flash (QK-ahead pipeline); [512,768) = featS;
// [768,1280) = tcf riders (Wf transpose -> wfT; shallow, needed only at FC).
// ---------------------------------------------------------------------------
__global__ __launch_bounds__(256) void flash_featS_kernel(
    const u16* __restrict__ Qb, const u16* __restrict__ Kb,
    const u16* __restrict__ Vt, u16* __restrict__ att,
    float* __restrict__ partials,
    const float* __restrict__ Wf, u16* __restrict__ wfT)
{
    __shared__ u16 sh[24576];   // 48 KB, carved per branch
    const int tid = threadIdx.x;
    const int lane = tid & 63, wave = tid >> 6;
    const int l15 = lane & 15, lg = lane >> 4;

    if ((int)blockIdx.x >= 768) {
        // ---------------- tcf rider: Wf[1024][512] -> wfT[512][1024] -------
        float* t = reinterpret_cast<float*>(sh);   // [32][33]
        const int rem = (int)blockIdx.x - 768;
        const int nt = (rem & 15) * 32, kt = (rem >> 4) * 32;
        {
            const int r = tid >> 3, c0 = (tid & 7) * 4;
            const float4 v = *reinterpret_cast<const float4*>(
                &Wf[(size_t)(kt + r) * 512 + nt + c0]);
            t[r * 33 + c0] = v.x; t[r * 33 + c0 + 1] = v.y;
            t[r * 33 + c0 + 2] = v.z; t[r * 33 + c0 + 3] = v.w;
        }
        __syncthreads();
        {
            const int nidx = tid >> 3, kc = (tid & 7) * 4;
            u16 o[4];
            #pragma unroll
            for (int j = 0; j < 4; ++j) o[j] = f2bf(t[(kc + j) * 33 + nidx]);
            *reinterpret_cast<ushort4*>(&wfT[(size_t)(nt + nidx) * 1024 + kt + kc]) =
                make_ushort4(o[0], o[1], o[2], o[3]);
        }
        return;
    }

    if ((int)blockIdx.x >= 512) {
        // ---------------- featS branch ----------------
        u16* KsT = sh;          // [kd][n], XOR-swizzled
        u16* QsT = sh + 4096;   // [qd][n], XOR-swizzled
        const int fid = (int)blockIdx.x - 512;
        const int ns = fid & 7, h = (fid >> 3) & 7, b = fid >> 6;
        const size_t hbase = (size_t)b * N_ * DK_ + (size_t)h * HK_;

        f32x4 acc[4] = {};
        for (int c = 0; c < 4; ++c) {
            const int n0 = ns * 256 + c * 64;
            __syncthreads();
            #pragma unroll
            for (int it = 0; it < 2; ++it) {
                const int idx = tid + it * 256;
                const int n = idx >> 3, d0 = (idx & 7) * 8;
                const u16x8 kv = *reinterpret_cast<const u16x8*>(
                    &Kb[hbase + (size_t)(n0 + n) * DK_ + d0]);
                const u16x8 qv = *reinterpret_cast<const u16x8*>(
                    &Qb[hbase + (size_t)(n0 + n) * DK_ + d0]);
                #pragma unroll
                for (int j = 0; j < 8; ++j) {
                    const int r = d0 + j;
                    const int cidx = n ^ ((r & 7) << 3);
                    KsT[r * 64 + cidx] = kv[j];
                    QsT[r * 64 + cidx] = qv[j];
                }
            }
            __syncthreads();
            #pragma unroll
            for (int ks = 0; ks < 2; ++ks) {
                const int kb2 = ks * 32 + lg * 8;
                const int ar = wave * 16 + l15;
                const short8 aK = *reinterpret_cast<const short8*>(
                    &KsT[ar * 64 + (kb2 ^ ((ar & 7) << 3))]);
                #pragma unroll
                for (int ni = 0; ni < 4; ++ni) {
                    const int br = ni * 16 + l15;
                    const short8 bQ = *reinterpret_cast<const short8*>(
                        &QsT[br * 64 + (kb2 ^ ((br & 7) << 3))]);
                    acc[ni] = __builtin_amdgcn_mfma_f32_16x16x32_bf16(
                        aK, bQ, acc[ni], 0, 0, 0);
                }
            }
        }
        const int bh = b * NH_ + h;
        #pragma unroll
        for (int ni = 0; ni < 4; ++ni)
            #pragma unroll
            for (int jj = 0; jj < 4; ++jj) {
                const int row = wave * 16 + lg * 4 + jj;
                partials[(((size_t)ns * 32 + bh) * 64 + row) * 64 + ni * 16 + l15] =
                    acc[ni][jj];
            }
        return;
    }

    // ---------------- flash branch ----------------
    u16* kb0 = sh;            // K tiles, XOR-swizzled rows
    u16* kb1 = sh + 4096;
    u16* vb0 = sh + 8192;     // V tiles [d][key], XOR-swizzled rows
    u16* vb1 = sh + 12288;
    u16* Ps  = sh + 16384;    // [q][key], XOR-swizzled rows (128 x 64)
    // grid(flash part) 512, XCD swizzle (64 blocks per XCD chunk)
    const int lbid = (((int)blockIdx.x & 7) << 6) + ((int)blockIdx.x >> 3);
    const int qt = lbid & 15, h = (lbid >> 4) & 7, b = lbid >> 7;

    short8 aq[2][2];
    #pragma unroll
    for (int qs = 0; qs < 2; ++qs) {
        const int qrow = qt * 128 + qs * 64 + wave * 16 + l15;
        const u16* qp = Qb + ((size_t)(b * N_ + qrow)) * DK_ + h * HK_ + lg * 8;
        aq[qs][0] = *reinterpret_cast<const short8*>(qp);
        aq[qs][1] = *reinterpret_cast<const short8*>(qp + 32);
    }
    short8 ones;
    #pragma unroll
    for (int i = 0; i < 8; ++i) ones[i] = (short)0x3F80;   // bf16 1.0

    const u16* Kbase = Kb + (size_t)b * N_ * DK_ + (size_t)h * HK_;
    const u16* Vbase = Vt + ((size_t)(b * NH_ + h)) * HK_ * N_;
    unsigned long long* Ps64 = reinterpret_cast<unsigned long long*>(Ps);

    f32x4 o[2][5] = {};   // o[qs][4] = row-sum accumulator (l), via ones-MFMA
    float m_[2] = {-1e30f, -1e30f};   // per-lane: running max of q = l15-row
    f32x4 SA[2][4], SB[2][4];

    // per-wave staging offsets (loop-invariant)
    const int ob0 = wave * 1024, oo0 = ob0 + lane * 16;
    const int row0s = oo0 >> 7;
    const int in0 = (oo0 & 127) ^ ((row0s & 7) << 4);

#define STAGE_K(ktile, KBUF) do {                                              \
    gload16((const char*)Kbase +                                               \
                ((size_t)((ktile) * 64 + row0s) * DK_) * 2 + in0,              \
            (char*)(KBUF) + ob0);                                              \
    gload16((const char*)Kbase +                                               \
                ((size_t)((ktile) * 64 + 32 + row0s) * DK_) * 2 + in0,         \
            (char*)(KBUF) + 4096 + ob0);                                       \
} while (0)

#define STAGE_V(ktile, VBUF) do {                                              \
    gload16((const char*)Vbase +                                               \
                ((size_t)row0s * N_ + (ktile) * 64) * 2 + in0,                 \
            (char*)(VBUF) + ob0);                                              \
    gload16((const char*)Vbase +                                               \
                ((size_t)(32 + row0s) * N_ + (ktile) * 64) * 2 + in0,          \
            (char*)(VBUF) + 4096 + ob0);                                       \
} while (0)

#define QK_STEP(S, KBUF) do {                                                  \
    _Pragma("unroll")                                                          \
    for (int qs = 0; qs < 2; ++qs)                                             \
        _Pragma("unroll")                                                      \
        for (int t = 0; t < 4; ++t)                                            \
            S[qs][t] = (f32x4){0.0f, 0.0f, 0.0f, 0.0f};                        \
    __builtin_amdgcn_s_setprio(1);                                             \
    _Pragma("unroll")                                                          \
    for (int ks = 0; ks < 2; ++ks) {                                           \
        const int kb2 = ks * 32 + lg * 8;                                      \
        _Pragma("unroll")                                                      \
        for (int t = 0; t < 4; ++t) {                                          \
            const int r = t * 16 + l15;                                        \
            const short8 bk = *reinterpret_cast<const short8*>(                \
                &(KBUF)[r * 64 + (kb2 ^ ((r & 7) << 3))]);                     \
            S[0][t] = __builtin_amdgcn_mfma_f32_16x16x32_bf16(                 \
                bk, aq[0][ks], S[0][t], 0, 0, 0);                              \
            S[1][t] = __builtin_amdgcn_mfma_f32_16x16x32_bf16(                 \
                bk, aq[1][ks], S[1][t], 0, 0, 0);                              \
        }                                                                      \
    }                                                                          \
    __builtin_amdgcn_s_setprio(0);                                             \
} while (0)

#define SMPV_STEP(S, VBUF) do {                                                \
    float rmax[2], cm;                                                         \
    _Pragma("unroll")                                                          \
    for (int qs = 0; qs < 2; ++qs) {                                           \
        float a0 = fmaxf(fmaxf(S[qs][0][0], S[qs][0][1]),                      \
                         fmaxf(S[qs][0][2], S[qs][0][3]));                     \
        float a1 = fmaxf(fmaxf(S[qs][1][0], S[qs][1][1]),                      \
                         fmaxf(S[qs][1][2], S[qs][1][3]));                     \
        float a2 = fmaxf(fmaxf(S[qs][2][0], S[qs][2][1]),                      \
                         fmaxf(S[qs][2][2], S[qs][2][3]));                     \
        float a3 = fmaxf(fmaxf(S[qs][3][0], S[qs][3][1]),                      \
                         fmaxf(S[qs][3][2], S[qs][3][3]));                     \
        rmax[qs] = fmaxf(fmaxf(a0, a1), fmaxf(a2, a3));                        \
    }                                                                          \
    cm = fmaxf(rmax[0] - m_[0], rmax[1] - m_[1]);                              \
    if (__any(cm > 8.0f)) {                                                    \
        _Pragma("unroll")                                                      \
        for (int qs = 0; qs < 2; ++qs) {                                       \
            float rm = rmax[qs];                                               \
            rm = fmaxf(rm, __shfl_xor(rm, 16));                                \
            rm = fmaxf(rm, __shfl_xor(rm, 32));                                \
            const float newm = fmaxf(m_[qs], rm);                              \
            const float fac = exp2f_fast(m_[qs] - newm);                       \
            m_[qs] = newm;                                                     \
            float facq[4];                                                     \
            _Pragma("unroll")                                                  \
            for (int jj = 0; jj < 4; ++jj)                                     \
                facq[jj] = __shfl(fac, lg * 4 + jj);                           \
            _Pragma("unroll")                                                  \
            for (int t = 0; t < 5; ++t)                                        \
                _Pragma("unroll")                                              \
                for (int jj = 0; jj < 4; ++jj)                                 \
                    o[qs][t][jj] *= facq[jj];                                  \
        }                                                                      \
    }                                                                          \
    _Pragma("unroll")                                                          \
    for (int qs = 0; qs < 2; ++qs) {                                           \
        const int prow = qs * 64 + wave * 16 + l15;                            \
        const int pb64 = prow * 16;                                            \
        const int sw1 = (prow & 7) << 1;                                       \
        _Pragma("unroll")                                                      \
        for (int t = 0; t < 4; ++t) {                                          \
            const float p0 = exp2f_fast(S[qs][t][0] - m_[qs]);                 \
            const float p1 = exp2f_fast(S[qs][t][1] - m_[qs]);                 \
            const float p2 = exp2f_fast(S[qs][t][2] - m_[qs]);                 \
            const float p3 = exp2f_fast(S[qs][t][3] - m_[qs]);                 \
            const uint32_t lo = cvtpk_bf16(p0, p1);                            \
            const uint32_t hi = cvtpk_bf16(p2, p3);                            \
            Ps64[pb64 + ((t * 4 + lg) ^ sw1)] =                                \
                (unsigned long long)lo | ((unsigned long long)hi << 32);       \
        }                                                                      \
    }                                                                          \
    __builtin_amdgcn_s_setprio(1);                                             \
    _Pragma("unroll")                                                          \
    for (int ks = 0; ks < 2; ++ks) {                                           \
        const int kb2 = ks * 32 + lg * 8;                                      \
        const int pr0 = wave * 16 + l15;                                       \
        const int pr1 = 64 + pr0;                                              \
        const short8 ap0 = *reinterpret_cast<const short8*>(                   \
            &Ps[pr0 * 64 + (kb2 ^ ((pr0 & 7) << 3))]);                         \
        const short8 ap1 = *reinterpret_cast<const short8*>(                   \
            &Ps[pr1 * 64 + (kb2 ^ ((pr1 & 7) << 3))]);                         \
        _Pragma("unroll")                                                      \
        for (int t = 0; t < 4; ++t) {                                          \
            const int dr = t * 16 + l15;                                       \
            const short8 bv = *reinterpret_cast<const short8*>(                \
                &(VBUF)[dr * 64 + (kb2 ^ ((dr & 7) << 3))]);                   \
            o[0][t] = __builtin_amdgcn_mfma_f32_16x16x32_bf16(                 \
                ap0, bv, o[0][t], 0, 0, 0);                                    \
            o[1][t] = __builtin_amdgcn_mfma_f32_16x16x32_bf16(                 \
                ap1, bv, o[1][t], 0, 0, 0);                                    \
        }                                                                      \
        o[0][4] = __builtin_amdgcn_mfma_f32_16x16x32_bf16(                     \
            ap0, ones, o[0][4], 0, 0, 0);                                      \
        o[1][4] = __builtin_amdgcn_mfma_f32_16x16x32_bf16(                     \
            ap1, ones, o[1][4], 0, 0, 0);                                      \
    }                                                                          \
    __builtin_amdgcn_s_setprio(0);                                             \
} while (0)

    // prologue: K(0),K(1),V(0) staged; score tile 0
    STAGE_K(0, kb0);
    STAGE_K(1, kb1);
    STAGE_V(0, vb0);
    __syncthreads();
    QK_STEP(SA, kb0);

    // half-iters t=0..29 (unroll 2: even uses kb0/vb0 for tile t, odd kb1/vb1)
    #pragma unroll 1
    for (int t2 = 0; t2 < 30; t2 += 2) {
        // t even
        __syncthreads();
        STAGE_K(t2 + 2, kb0);
        STAGE_V(t2 + 1, vb1);
        QK_STEP(SB, kb1);          // tile t+1
        SMPV_STEP(SA, vb0);        // tile t
        // t odd
        __syncthreads();
        STAGE_K(t2 + 3, kb1);
        STAGE_V(t2 + 2, vb0);
        QK_STEP(SA, kb0);          // tile t+2
        SMPV_STEP(SB, vb1);        // tile t+1
    }
    // t = 30 (even): QK(31), SMPV(30); stage only V(31)
    __syncthreads();
    STAGE_V(31, vb1);
    QK_STEP(SB, kb1);
    SMPV_STEP(SA, vb0);
    // t = 31 (odd): SMPV(31)
    __syncthreads();
    SMPV_STEP(SB, vb1);

#undef STAGE_K
#undef STAGE_V
#undef QK_STEP
#undef SMPV_STEP

    #pragma unroll
    for (int qs = 0; qs < 2; ++qs)
        #pragma unroll
        for (int jj = 0; jj < 4; ++jj) {
            const float inv = 1.0f / o[qs][4][jj];
            const size_t row = (size_t)b * N_ + qt * 128 + qs * 64 + wave * 16 + lg * 4 + jj;
            #pragma unroll
            for (int t = 0; t < 4; ++t)
                att[row * (2 * DK_) + h * HK_ + t * 16 + l15] =
                    f2bf_fast(o[qs][t][jj] * inv);
        }
}

// sum partials, softmax over qd, write distfT[bh][qd][kd] bf16.
// Grid (32, 4): bh x 16-kd-row groups.
__global__ __launch_bounds__(256) void featSM_kernel(
    const float* __restrict__ partials, u16* __restrict__ distfT)
{
    const int bh = blockIdx.x, rg = blockIdx.y, tid = threadIdx.x;
    const int r = rg * 16 + (tid >> 4);   // kd row
    const int tl = tid & 15;              // qd group: qd = tl*4 .. +3
    float v[4] = {0.0f, 0.0f, 0.0f, 0.0f};
    for (int s = 0; s < 8; ++s) {
        const float4 a = *reinterpret_cast<const float4*>(
            &partials[(((size_t)s * 32 + bh) * 64 + r) * 64 + tl * 4]);
        v[0] += a.x; v[1] += a.y; v[2] += a.z; v[3] += a.w;
    }
    float m = fmaxf(fmaxf(v[0], v[1]), fmaxf(v[2], v[3]));
    m = fmaxf(m, __shfl_xor(m, 1));
    m = fmaxf(m, __shfl_xor(m, 2));
    m = fmaxf(m, __shfl_xor(m, 4));
    m = fmaxf(m, __shfl_xor(m, 8));
    float sum = 0.0f;
    #pragma unroll
    for (int j = 0; j < 4; ++j) { v[j] = exp2f_fast(v[j] - m); sum += v[j]; }
    sum += __shfl_xor(sum, 1);
    sum += __shfl_xor(sum, 2);
    sum += __shfl_xor(sum, 4);
    sum += __shfl_xor(sum, 8);
    const float inv = 1.0f / sum;
    #pragma unroll
    for (int j = 0; j < 4; ++j)
        distfT[(size_t)bh * 4096 + (tl * 4 + j) * 64 + r] = f2bf_fast(v[j] * inv);
}

// att_f[n,q] = sum_d V[n,d] * distf[d,q] -> att[:, 512+h*64+q] (MFMA).
// Grid (32, NH, B): one 64-row chunk per block.
__global__ __launch_bounds__(256) void featAV_mfma(
    const u16* __restrict__ V, const u16* __restrict__ distfT,
    u16* __restrict__ att)
{
    __shared__ u16 Bs[64 * 64];   // distfT[q][d], XOR-swizzled
    __shared__ u16 As[64 * 64];   // V rows
    const int tid = threadIdx.x;
    const int lane = tid & 63, wave = tid >> 6;
    const int l15 = lane & 15, lg = lane >> 4;
    const int ns = blockIdx.x, h = blockIdx.y, b = blockIdx.z;
    const int bh = b * NH_ + h;
    const int n0 = ns * 64;

    #pragma unroll
    for (int it = 0; it < 2; ++it) {
        const int idx = tid + it * 256;
        const int r = idx >> 3, c0 = (idx & 7) * 8;
        const u16x8 dv = *reinterpret_cast<const u16x8*>(
            &distfT[(size_t)bh * 4096 + r * 64 + c0]);
        *reinterpret_cast<u16x8*>(&Bs[r * 64 + (c0 ^ ((r & 7) << 3))]) = dv;
    }
    #pragma unroll
    for (int i = 0; i < 2; ++i) {
        const int ob = (wave * 2 + i) * 1024;
        const int o_ = ob + lane * 16;
        const int row = o_ >> 7;
        const int inner = (o_ & 127) ^ ((row & 7) << 4);
        gload16((const char*)V + ((size_t)(b * N_ + n0 + row) * DK_ + h * HK_) * 2 + inner,
                (char*)As + ob);
    }
    __syncthreads();
    f32x4 acc[4] = {};
    #pragma unroll
    for (int ks = 0; ks < 2; ++ks) {
        const int kb2 = ks * 32 + lg * 8;
        const int ar = wave * 16 + l15;
        const short8 av = *reinterpret_cast<const short8*>(
            &As[ar * 64 + (kb2 ^ ((ar & 7) << 3))]);
        #pragma unroll
        for (int ni = 0; ni < 4; ++ni) {
            const int br = ni * 16 + l15;
            const short8 bd = *reinterpret_cast<const short8*>(
                &Bs[br * 64 + (kb2 ^ ((br & 7) << 3))]);
            acc[ni] = __builtin_amdgcn_mfma_f32_16x16x32_bf16(av, bd, acc[ni], 0, 0, 0);
        }
    }
    #pragma unroll
    for (int ni = 0; ni < 4; ++ni)
        #pragma unroll
        for (int jj = 0; jj < 4; ++jj)
            att[((size_t)b * N_ + n0 + wave * 16 + lg * 4 + jj) * (2 * DK_)
                + 512 + h * HK_ + ni * 16 + l15] = f2bf_fast(acc[ni][jj]);
}

// ---------------------------------------------------------------------------
// LayerNorm, wave-per-row: grid 2048 x 256 thr (4 waves = 4 rows/block).
// ---------------------------------------------------------------------------
__global__ __launch_bounds__(256) void ln_kernel(
    const u16* __restrict__ fc, const float* __restrict__ gamma,
    const float* __restrict__ beta, float* __restrict__ out)
{
    const int row = blockIdx.x * 4 + (threadIdx.x >> 6);
    const int lane = threadIdx.x & 63;
    const int c = lane * 8;
    const u16x8 v = *reinterpret_cast<const u16x8*>(&fc[(size_t)row * D_ + c]);
    float f[8];
    float s = 0.0f, sq = 0.0f;
    #pragma unroll
    for (int j = 0; j < 8; ++j) {
        f[j] = b2f(v[j]);
        s += f[j];
        sq = fmaf(f[j], f[j], sq);
    }
    #pragma unroll
    for (int off = 32; off >= 1; off >>= 1) {
        s  += __shfl_xor(s, off);
        sq += __shfl_xor(sq, off);
    }
    const float mu = s * (1.0f / D_);
    const float var = sq * (1.0f / D_) - mu * mu;
    const float rstd = rsqrtf(var + LN_EPS_);
    const float4 g0 = *reinterpret_cast<const float4*>(&gamma[c]);
    const float4 g1 = *reinterpret_cast<const float4*>(&gamma[c + 4]);
    const float4 b0 = *reinterpret_cast<const float4*>(&beta[c]);
    const float4 b1 = *reinterpret_cast<const float4*>(&beta[c + 4]);
    const float gg[8] = {g0.x, g0.y, g0.z, g0.w, g1.x, g1.y, g1.z, g1.w};
    const float bb[8] = {b0.x, b0.y, b0.z, b0.w, b1.x, b1.y, b1.z, b1.w};
    float4 o0, o1;
    o0.x = (f[0] - mu) * rstd * gg[0] + bb[0];
    o0.y = (f[1] - mu) * rstd * gg[1] + bb[1];
    o0.z = (f[2] - mu) * rstd * gg[2] + bb[2];
    o0.w = (f[3] - mu) * rstd * gg[3] + bb[3];
    o1.x = (f[4] - mu) * rstd * gg[4] + bb[4];
    o1.y = (f[5] - mu) * rstd * gg[5] + bb[5];
    o1.z = (f[6] - mu) * rstd * gg[6] + bb[6];
    o1.w = (f[7] - mu) * rstd * gg[7] + bb[7];
    *reinterpret_cast<float4*>(&out[(size_t)row * D_ + c]) = o0;
    *reinterpret_cast<float4*>(&out[(size_t)row * D_ + c + 4]) = o1;
}

// ---------------------------------------------------------------------------
extern "C" void kernel_launch(void* const* d_in, const int* in_sizes, int n_in,
                              void* d_out, int out_size, void* d_ws, size_t ws_size,
                              hipStream_t stream)
{
    (void)in_sizes; (void)n_in; (void)out_size; (void)ws_size;
    const float* x     = (const float*)d_in[0];
    const float* Wq    = (const float*)d_in[1];
    const float* Wk    = (const float*)d_in[2];
    const float* Wv    = (const float*)d_in[3];
    const float* Wf    = (const float*)d_in[4];
    const float* bf    = (const float*)d_in[5];
    const float* gamma = (const float*)d_in[6];
    const float* beta  = (const float*)d_in[7];
    float* out = (float*)d_out;

    char* w = (char*)d_ws;
    const size_t SZE = (size_t)B_ * N_ * DK_;            // 4,194,304 elems
    u16* wqkvT  = (u16*)w;   w += (size_t)1536 * 512 * 2;
    u16* wfT    = (u16*)w;   w += (size_t)512 * 1024 * 2;
    u16* qb     = (u16*)w;   w += SZE * 2;
    u16* kb     = (u16*)w;   w += SZE * 2;
    u16* vb     = (u16*)w;   w += SZE * 2;
    u16* vt     = (u16*)w;   w += SZE * 2;
    u16* attb   = (u16*)w;   w += SZE * 2 * 2;
    float* partials = (float*)w; w += (size_t)8 * 32 * 4096 * 4;   // 4 MB
    u16* distfT = (u16*)w;   w += (size_t)32 * 4096 * 2;
    u16* fcout  = (u16*)w;   // 8192*512*2 = 8.4 MB

    const dim3 blk(256);

    // prep: Wq/Wk/Wv transposes only (768 blocks)
    prep_kernel<<<dim3(768), blk, 0, stream>>>(Wq, Wk, Wv, wqkvT);

    // fused QKV projection: reads x fp32 directly (in-kernel convert),
    // 2-phase pipelined; q pre-scaled; v dual-written
    gemm_qkv_kernel<<<dim3(1536), blk, 0, stream>>>(x, wqkvT, qb, kb, vb, vt);

    // FAT launch: flash (512) + featS (256) + tcf riders (512)
    flash_featS_kernel<<<dim3(1280), blk, 0, stream>>>(
        qb, kb, vt, attb, partials, Wf, wfT);

    featSM_kernel<<<dim3(32, 4), blk, 0, stream>>>(partials, distfT);
    featAV_mfma<<<dim3(32, NH_, B_), blk, 0, stream>>>(vb, distfT, attb);

    // FC + bias + relu + resid -> bf16 fcout (2-phase pipelined)
    gemm_fc_kernel<<<dim3(512), blk, 0, stream>>>(attb, wfT, fcout, bf, x);

    // LayerNorm (wave-per-row)
    ln_kernel<<<dim3(2048), blk, 0, stream>>>(fcout, gamma, beta, out);
}

// Round 21
// 116.011 us; speedup vs baseline: 1.0342x; 1.0342x over previous
//
#include <hip/hip_runtime.h>
#include <math.h>
#include <stdint.h>

#define B_   4
#define N_   2048
#define D_   512
#define DK_  512
#define NH_  8
#define HK_  64
#define LN_EPS_ 1e-5f
// softmax runs in exp2 domain: Q is pre-scaled by 1/sqrt(64) * log2(e)
#define QS_  0.18033688011112042f

typedef unsigned short u16;
typedef __attribute__((ext_vector_type(8))) short short8;
typedef __attribute__((ext_vector_type(4))) float f32x4;
typedef __attribute__((ext_vector_type(8))) unsigned short u16x8;

__device__ __forceinline__ u16 f2bf(float x) {          // RNE
    uint32_t u = __builtin_bit_cast(uint32_t, x);
    return (u16)((u + 0x7fffu + ((u >> 16) & 1u)) >> 16);
}
__device__ __forceinline__ u16 f2bf_fast(float x) {     // round-half-up (2 ops)
    return (u16)((__builtin_bit_cast(uint32_t, x) + 0x8000u) >> 16);
}
__device__ __forceinline__ float b2f(u16 v) {
    return __builtin_bit_cast(float, (uint32_t)v << 16);
}
// HW packed bf16 convert: lo -> bits[15:0], hi -> bits[31:16] (T12 recipe)
__device__ __forceinline__ uint32_t cvtpk_bf16(float lo, float hi) {
    uint32_t r;
    asm("v_cvt_pk_bf16_f32 %0, %1, %2" : "=v"(r) : "v"(lo), "v"(hi));
    return r;
}
__device__ __forceinline__ float exp2f_fast(float x) {
    return __builtin_amdgcn_exp2f(x);
}

// async global->LDS, 16B/lane; LDS dest = wave-uniform base + lane*16
__device__ __forceinline__ void gload16(const void* g, void* l) {
    __builtin_amdgcn_global_load_lds(
        reinterpret_cast<const __attribute__((address_space(1))) void*>(
            reinterpret_cast<uintptr_t>(g)),
        reinterpret_cast<__attribute__((address_space(3))) void*>(
            static_cast<uint32_t>(reinterpret_cast<uintptr_t>(l))),
        16, 0, 0);
}

// ---------------------------------------------------------------------------
// Merged prep: [0,2048) conv x->bf16; [2048,2816) tc3 (Wq/Wk/Wv transpose);
// [2816,3328) tcf (Wf transpose). Block-uniform branch. (R12-proven.)
// ---------------------------------------------------------------------------
__global__ __launch_bounds__(256) void prep_kernel(
    const float* __restrict__ x, const float* __restrict__ Wq,
    const float* __restrict__ Wk, const float* __restrict__ Wv,
    const float* __restrict__ Wf, u16* __restrict__ xb,
    u16* __restrict__ wqkvT, u16* __restrict__ wfT)
{
    __shared__ float t[32][33];
    const int bid = blockIdx.x, tid = threadIdx.x;
    if (bid < 2048) {
        const int i = (bid * 256 + tid) * 8;
        const float4 a = *reinterpret_cast<const float4*>(&x[i]);
        const float4 b = *reinterpret_cast<const float4*>(&x[i + 4]);
        u16x8 o;
        o[0] = f2bf(a.x); o[1] = f2bf(a.y); o[2] = f2bf(a.z); o[3] = f2bf(a.w);
        o[4] = f2bf(b.x); o[5] = f2bf(b.y); o[6] = f2bf(b.z); o[7] = f2bf(b.w);
        *reinterpret_cast<u16x8*>(&xb[i]) = o;
        return;
    }
    const float* W;
    u16* dst;
    int K, Nc, nt, kt;
    if (bid < 2816) {
        const int z = (bid - 2048) >> 8, rem = (bid - 2048) & 255;
        W = z == 0 ? Wq : (z == 1 ? Wk : Wv);
        dst = wqkvT + (size_t)z * 512 * 512;
        K = 512; Nc = 512;
        nt = (rem & 15) * 32; kt = (rem >> 4) * 32;
    } else {
        const int rem = bid - 2816;
        W = Wf; dst = wfT; K = 1024; Nc = 512;
        nt = (rem & 15) * 32; kt = (rem >> 4) * 32;
    }
    {
        const int r = tid >> 3, c0 = (tid & 7) * 4;
        const float4 v = *reinterpret_cast<const float4*>(
            &W[(size_t)(kt + r) * Nc + nt + c0]);
        t[r][c0] = v.x; t[r][c0 + 1] = v.y; t[r][c0 + 2] = v.z; t[r][c0 + 3] = v.w;
    }
    __syncthreads();
    {
        const int nidx = tid >> 3, kc = (tid & 7) * 4;
        u16 o[4];
        #pragma unroll
        for (int j = 0; j < 4; ++j) o[j] = f2bf(t[kc + j][nidx]);
        *reinterpret_cast<ushort4*>(&dst[(size_t)(nt + nidx) * K + kt + kc]) =
            make_ushort4(o[0], o[1], o[2], o[3]);
    }
}

// ---------------------------------------------------------------------------
// QKV GEMM: [8192,512] @ wqkvT[1536,512]^T -> q/k/v, 64x128 tile, BK=64,
// 2-phase static double-buffer. Split epilogue: q pre-scaled by QS_,
// v dual-written to vb and per-head-transposed vt. Grid 1536, XCD-swizzled.
// ---------------------------------------------------------------------------
__global__ __launch_bounds__(256) void gemm_qkv_kernel(
    const u16* __restrict__ A, const u16* __restrict__ Bt,
    u16* __restrict__ qb, u16* __restrict__ kb,
    u16* __restrict__ vb, u16* __restrict__ vt)
{
    __shared__ u16 As0[64 * 64], As1[64 * 64];
    __shared__ u16 Bs0[128 * 64], Bs1[128 * 64];
    const int tid = threadIdx.x;
    const int lane = tid & 63, wave = tid >> 6;
    const int wm = wave >> 1, wn = wave & 1;
    const int l15 = lane & 15, lg = lane >> 4;
    const int bid = ((int)blockIdx.x & 7) * 192 + ((int)blockIdx.x >> 3);
    const int nt = (bid % 12) * 128;         // 1536/128 = 12 n-tiles
    const int mt = (bid / 12) * 64;

    f32x4 acc[2][4] = {};

#define QKV_STAGE(kt, AS, BS) do {                                             \
    _Pragma("unroll")                                                          \
    for (int i_ = 0; i_ < 2; ++i_) {                                           \
        const int ob_ = (wave * 2 + i_) * 1024;                                \
        const int o_ = ob_ + lane * 16;                                        \
        const int row_ = o_ >> 7;                                              \
        const int inner_ = (o_ & 127) ^ ((row_ & 7) << 4);                     \
        gload16((const char*)A + ((size_t)(mt + row_) * 512 + (kt) * 64) * 2   \
                    + inner_, (char*)(AS) + ob_);                              \
    }                                                                          \
    _Pragma("unroll")                                                          \
    for (int i_ = 0; i_ < 4; ++i_) {                                           \
        const int ob_ = (wave * 4 + i_) * 1024;                                \
        const int o_ = ob_ + lane * 16;                                        \
        const int row_ = o_ >> 7;                                              \
        const int inner_ = (o_ & 127) ^ ((row_ & 7) << 4);                     \
        gload16((const char*)Bt + ((size_t)(nt + row_) * 512 + (kt) * 64) * 2  \
                    + inner_, (char*)(BS) + ob_);                              \
    }                                                                          \
} while (0)

#define QKV_COMP(AS, BS) do {                                                  \
    _Pragma("unroll")                                                          \
    for (int ks = 0; ks < 2; ++ks) {                                           \
        const int kb2 = ks * 32 + lg * 8;                                      \
        short8 af[2], bfr[4];                                                  \
        _Pragma("unroll")                                                      \
        for (int mi = 0; mi < 2; ++mi) {                                       \
            const int r = wm * 32 + mi * 16 + l15;                             \
            af[mi] = *reinterpret_cast<const short8*>(                         \
                &(AS)[r * 64 + (kb2 ^ ((r & 7) << 3))]);                       \
        }                                                                      \
        _Pragma("unroll")                                                      \
        for (int ni = 0; ni < 4; ++ni) {                                       \
            const int r = wn * 64 + ni * 16 + l15;                             \
            bfr[ni] = *reinterpret_cast<const short8*>(                        \
                &(BS)[r * 64 + (kb2 ^ ((r & 7) << 3))]);                       \
        }                                                                      \
        _Pragma("unroll")                                                      \
        for (int mi = 0; mi < 2; ++mi)                                         \
            _Pragma("unroll")                                                  \
            for (int ni = 0; ni < 4; ++ni)                                     \
                acc[mi][ni] = __builtin_amdgcn_mfma_f32_16x16x32_bf16(         \
                    af[mi], bfr[ni], acc[mi][ni], 0, 0, 0);                    \
    }                                                                          \
} while (0)

    QKV_STAGE(0, As0, Bs0);
    __syncthreads();
    #pragma unroll 1
    for (int kt = 0; kt < 8; kt += 2) {
        QKV_STAGE(kt + 1, As1, Bs1);        // kt+1 <= 7 always
        QKV_COMP(As0, Bs0);
        __syncthreads();
        if (kt + 2 < 8) QKV_STAGE(kt + 2, As0, Bs0);
        QKV_COMP(As1, Bs1);
        __syncthreads();
    }
#undef QKV_STAGE
#undef QKV_COMP

    #pragma unroll
    for (int mi = 0; mi < 2; ++mi) {
        #pragma unroll
        for (int ni = 0; ni < 4; ++ni) {
            const int col = nt + wn * 64 + ni * 16 + l15;
            const int row0 = mt + wm * 32 + mi * 16 + lg * 4;
            if (col < 512) {
                #pragma unroll
                for (int jj = 0; jj < 4; ++jj)
                    qb[(size_t)(row0 + jj) * 512 + col] =
                        f2bf(acc[mi][ni][jj] * QS_);
            } else if (col < 1024) {
                #pragma unroll
                for (int jj = 0; jj < 4; ++jj)
                    kb[(size_t)(row0 + jj) * 512 + col - 512] =
                        f2bf(acc[mi][ni][jj]);
            } else {
                const int dfull = col - 1024;
                const int hh = dfull >> 6, dd = dfull & 63;
                const int bb = row0 >> 11, nn = row0 & 2047;
                u16 o4[4];
                #pragma unroll
                for (int jj = 0; jj < 4; ++jj) {
                    o4[jj] = f2bf(acc[mi][ni][jj]);
                    vb[(size_t)(row0 + jj) * 512 + dfull] = o4[jj];
                }
                *reinterpret_cast<ushort4*>(
                    &vt[(((size_t)(bb * NH_ + hh)) * HK_ + dd) * N_ + nn]) =
                    make_ushort4(o4[0], o4[1], o4[2], o4[3]);
            }
        }
    }
}

// ---------------------------------------------------------------------------
// FC GEMM: [8192,1024] @ wfT[512,1024]^T -> bf16 [8192,512], 64x128 tile,
// BK=64, 2-phase static double-buffer. bias + relu + resid epilogue.
// ---------------------------------------------------------------------------
__global__ __launch_bounds__(256) void gemm_fc_kernel(
    const u16* __restrict__ A, const u16* __restrict__ Bt,
    u16* __restrict__ C, const float* __restrict__ bias,
    const float* __restrict__ resid)
{
    __shared__ u16 As0[64 * 64], As1[64 * 64];
    __shared__ u16 Bs0[128 * 64], Bs1[128 * 64];
    const int tid = threadIdx.x;
    const int lane = tid & 63, wave = tid >> 6;
    const int wm = wave >> 1, wn = wave & 1;
    const int l15 = lane & 15, lg = lane >> 4;
    const int bid = ((int)blockIdx.x & 7) * 64 + ((int)blockIdx.x >> 3);
    const int nt = (bid & 3) * 128;          // 512/128 = 4 n-tiles
    const int mt = (bid >> 2) * 64;

    f32x4 acc[2][4] = {};

#define FC_STAGE(kt, AS, BS) do {                                              \
    _Pragma("unroll")                                                          \
    for (int i_ = 0; i_ < 2; ++i_) {                                           \
        const int ob_ = (wave * 2 + i_) * 1024;                                \
        const int o_ = ob_ + lane * 16;                                        \
        const int row_ = o_ >> 7;                                              \
        const int inner_ = (o_ & 127) ^ ((row_ & 7) << 4);                     \
        gload16((const char*)A + ((size_t)(mt + row_) * 1024 + (kt) * 64) * 2  \
                    + inner_, (char*)(AS) + ob_);                              \
    }                                                                          \
    _Pragma("unroll")                                                          \
    for (int i_ = 0; i_ < 4; ++i_) {                                           \
        const int ob_ = (wave * 4 + i_) * 1024;                                \
        const int o_ = ob_ + lane * 16;                                        \
        const int row_ = o_ >> 7;                                              \
        const int inner_ = (o_ & 127) ^ ((row_ & 7) << 4);                     \
        gload16((const char*)Bt + ((size_t)(nt + row_) * 1024 + (kt) * 64) * 2 \
                    + inner_, (char*)(BS) + ob_);                              \
    }                                                                          \
} while (0)

#define FC_COMP(AS, BS) do {                                                   \
    _Pragma("unroll")                                                          \
    for (int ks = 0; ks < 2; ++ks) {                                           \
        const int kb2 = ks * 32 + lg * 8;                                      \
        short8 af[2], bfr[4];                                                  \
        _Pragma("unroll")                                                      \
        for (int mi = 0; mi < 2; ++mi) {                                       \
            const int r = wm * 32 + mi * 16 + l15;                             \
            af[mi] = *reinterpret_cast<const short8*>(                         \
                &(AS)[r * 64 + (kb2 ^ ((r & 7) << 3))]);                       \
        }                                                                      \
        _Pragma("unroll")                                                      \
        for (int ni = 0; ni < 4; ++ni) {                                       \
            const int r = wn * 64 + ni * 16 + l15;                             \
            bfr[ni] = *reinterpret_cast<const short8*>(                        \
                &(BS)[r * 64 + (kb2 ^ ((r & 7) << 3))]);                       \
        }                                                                      \
        _Pragma("unroll")                                                      \
        for (int mi = 0; mi < 2; ++mi)                                         \
            _Pragma("unroll")                                                  \
            for (int ni = 0; ni < 4; ++ni)                                     \
                acc[mi][ni] = __builtin_amdgcn_mfma_f32_16x16x32_bf16(         \
                    af[mi], bfr[ni], acc[mi][ni], 0, 0, 0);                    \
    }                                                                          \
} while (0)

    FC_STAGE(0, As0, Bs0);
    __syncthreads();
    #pragma unroll 1
    for (int kt = 0; kt < 16; kt += 2) {
        FC_STAGE(kt + 1, As1, Bs1);         // kt+1 <= 15 always
        FC_COMP(As0, Bs0);
        __syncthreads();
        if (kt + 2 < 16) FC_STAGE(kt + 2, As0, Bs0);
        FC_COMP(As1, Bs1);
        __syncthreads();
    }
#undef FC_STAGE
#undef FC_COMP

    #pragma unroll
    for (int mi = 0; mi < 2; ++mi) {
        #pragma unroll
        for (int ni = 0; ni < 4; ++ni) {
            const int col = nt + wn * 64 + ni * 16 + l15;
            const int row0 = mt + wm * 32 + mi * 16 + lg * 4;
            #pragma unroll
            for (int jj = 0; jj < 4; ++jj) {
                const size_t row = (size_t)(row0 + jj);
                float v = acc[mi][ni][jj];
                v += bias[col];
                v = fmaxf(v, 0.0f);
                v += resid[row * 512 + col];
                C[row * 512 + col] = f2bf(v);
            }
        }
    }
}

// ---------------------------------------------------------------------------
// FAT kernel: blocks [0,512) = flash (QK-ahead pipeline); [512,768) = featS.
// ---------------------------------------------------------------------------
__global__ __launch_bounds__(256) void flash_featS_kernel(
    const u16* __restrict__ Qb, const u16* __restrict__ Kb,
    const u16* __restrict__ Vt, u16* __restrict__ att,
    float* __restrict__ partials)
{
    __shared__ u16 sh[24576];   // 48 KB, carved per branch
    const int tid = threadIdx.x;
    const int lane = tid & 63, wave = tid >> 6;
    const int l15 = lane & 15, lg = lane >> 4;

    if ((int)blockIdx.x >= 512) {
        // ---------------- featS branch ----------------
        u16* KsT = sh;          // [kd][n], XOR-swizzled
        u16* QsT = sh + 4096;   // [qd][n], XOR-swizzled
        const int fid = (int)blockIdx.x - 512;
        const int ns = fid & 7, h = (fid >> 3) & 7, b = fid >> 6;
        const size_t hbase = (size_t)b * N_ * DK_ + (size_t)h * HK_;

        f32x4 acc[4] = {};
        for (int c = 0; c < 4; ++c) {
            const int n0 = ns * 256 + c * 64;
            __syncthreads();
            #pragma unroll
            for (int it = 0; it < 2; ++it) {
                const int idx = tid + it * 256;
                const int n = idx >> 3, d0 = (idx & 7) * 8;
                const u16x8 kv = *reinterpret_cast<const u16x8*>(
                    &Kb[hbase + (size_t)(n0 + n) * DK_ + d0]);
                const u16x8 qv = *reinterpret_cast<const u16x8*>(
                    &Qb[hbase + (size_t)(n0 + n) * DK_ + d0]);
                #pragma unroll
                for (int j = 0; j < 8; ++j) {
                    const int r = d0 + j;
                    const int cidx = n ^ ((r & 7) << 3);
                    KsT[r * 64 + cidx] = kv[j];
                    QsT[r * 64 + cidx] = qv[j];
                }
            }
            __syncthreads();
            #pragma unroll
            for (int ks = 0; ks < 2; ++ks) {
                const int kb2 = ks * 32 + lg * 8;
                const int ar = wave * 16 + l15;
                const short8 aK = *reinterpret_cast<const short8*>(
                    &KsT[ar * 64 + (kb2 ^ ((ar & 7) << 3))]);
                #pragma unroll
                for (int ni = 0; ni < 4; ++ni) {
                    const int br = ni * 16 + l15;
                    const short8 bQ = *reinterpret_cast<const short8*>(
                        &QsT[br * 64 + (kb2 ^ ((br & 7) << 3))]);
                    acc[ni] = __builtin_amdgcn_mfma_f32_16x16x32_bf16(
                        aK, bQ, acc[ni], 0, 0, 0);
                }
            }
        }
        const int bh = b * NH_ + h;
        #pragma unroll
        for (int ni = 0; ni < 4; ++ni)
            #pragma unroll
            for (int jj = 0; jj < 4; ++jj) {
                const int row = wave * 16 + lg * 4 + jj;
                partials[(((size_t)ns * 32 + bh) * 64 + row) * 64 + ni * 16 + l15] =
                    acc[ni][jj];
            }
        return;
    }

    // ---------------- flash branch ----------------
    u16* kb0 = sh;            // K tiles, XOR-swizzled rows
    u16* kb1 = sh + 4096;
    u16* vb0 = sh + 8192;     // V tiles [d][key], XOR-swizzled rows
    u16* vb1 = sh + 12288;
    u16* Ps  = sh + 16384;    // [q][key], XOR-swizzled rows (128 x 64)
    // grid(flash part) 512, XCD swizzle (64 blocks per XCD chunk)
    const int lbid = (((int)blockIdx.x & 7) << 6) + ((int)blockIdx.x >> 3);
    const int qt = lbid & 15, h = (lbid >> 4) & 7, b = lbid >> 7;

    short8 aq[2][2];
    #pragma unroll
    for (int qs = 0; qs < 2; ++qs) {
        const int qrow = qt * 128 + qs * 64 + wave * 16 + l15;
        const u16* qp = Qb + ((size_t)(b * N_ + qrow)) * DK_ + h * HK_ + lg * 8;
        aq[qs][0] = *reinterpret_cast<const short8*>(qp);
        aq[qs][1] = *reinterpret_cast<const short8*>(qp + 32);
    }
    short8 ones;
    #pragma unroll
    for (int i = 0; i < 8; ++i) ones[i] = (short)0x3F80;   // bf16 1.0

    const u16* Kbase = Kb + (size_t)b * N_ * DK_ + (size_t)h * HK_;
    const u16* Vbase = Vt + ((size_t)(b * NH_ + h)) * HK_ * N_;
    unsigned long long* Ps64 = reinterpret_cast<unsigned long long*>(Ps);

    f32x4 o[2][5] = {};   // o[qs][4] = row-sum accumulator (l), via ones-MFMA
    float m_[2] = {-1e30f, -1e30f};   // per-lane: running max of q = l15-row
    f32x4 SA[2][4], SB[2][4];

    // per-wave staging offsets (loop-invariant)
    const int ob0 = wave * 1024, oo0 = ob0 + lane * 16;
    const int row0s = oo0 >> 7;
    const int in0 = (oo0 & 127) ^ ((row0s & 7) << 4);

#define STAGE_K(ktile, KBUF) do {                                              \
    gload16((const char*)Kbase +                                               \
                ((size_t)((ktile) * 64 + row0s) * DK_) * 2 + in0,              \
            (char*)(KBUF) + ob0);                                              \
    gload16((const char*)Kbase +                                               \
                ((size_t)((ktile) * 64 + 32 + row0s) * DK_) * 2 + in0,         \
            (char*)(KBUF) + 4096 + ob0);                                       \
} while (0)

#define STAGE_V(ktile, VBUF) do {                                              \
    gload16((const char*)Vbase +                                               \
                ((size_t)row0s * N_ + (ktile) * 64) * 2 + in0,                 \
            (char*)(VBUF) + ob0);                                              \
    gload16((const char*)Vbase +                                               \
                ((size_t)(32 + row0s) * N_ + (ktile) * 64) * 2 + in0,          \
            (char*)(VBUF) + 4096 + ob0);                                       \
} while (0)

#define QK_STEP(S, KBUF) do {                                                  \
    _Pragma("unroll")                                                          \
    for (int qs = 0; qs < 2; ++qs)                                             \
        _Pragma("unroll")                                                      \
        for (int t = 0; t < 4; ++t)                                            \
            S[qs][t] = (f32x4){0.0f, 0.0f, 0.0f, 0.0f};                        \
    __builtin_amdgcn_s_setprio(1);                                             \
    _Pragma("unroll")                                                          \
    for (int ks = 0; ks < 2; ++ks) {                                           \
        const int kb2 = ks * 32 + lg * 8;                                      \
        _Pragma("unroll")                                                      \
        for (int t = 0; t < 4; ++t) {                                          \
            const int r = t * 16 + l15;                                        \
            const short8 bk = *reinterpret_cast<const short8*>(                \
                &(KBUF)[r * 64 + (kb2 ^ ((r & 7) << 3))]);                     \
            S[0][t] = __builtin_amdgcn_mfma_f32_16x16x32_bf16(                 \
                bk, aq[0][ks], S[0][t], 0, 0, 0);                              \
            S[1][t] = __builtin_amdgcn_mfma_f32_16x16x32_bf16(                 \
                bk, aq[1][ks], S[1][t], 0, 0, 0);                              \
        }                                                                      \
    }                                                                          \
    __builtin_amdgcn_s_setprio(0);                                             \
} while (0)

#define SMPV_STEP(S, VBUF) do {                                                \
    float rmax[2], cm;                                                         \
    _Pragma("unroll")                                                          \
    for (int qs = 0; qs < 2; ++qs) {                                           \
        float a0 = fmaxf(fmaxf(S[qs][0][0], S[qs][0][1]),                      \
                         fmaxf(S[qs][0][2], S[qs][0][3]));                     \
        float a1 = fmaxf(fmaxf(S[qs][1][0], S[qs][1][1]),                      \
                         fmaxf(S[qs][1][2], S[qs][1][3]));                     \
        float a2 = fmaxf(fmaxf(S[qs][2][0], S[qs][2][1]),                      \
                         fmaxf(S[qs][2][2], S[qs][2][3]));                     \
        float a3 = fmaxf(fmaxf(S[qs][3][0], S[qs][3][1]),                      \
                         fmaxf(S[qs][3][2], S[qs][3][3]));                     \
        rmax[qs] = fmaxf(fmaxf(a0, a1), fmaxf(a2, a3));                        \
    }                                                                          \
    cm = fmaxf(rmax[0] - m_[0], rmax[1] - m_[1]);                              \
    if (__any(cm > 8.0f)) {                                                    \
        _Pragma("unroll")                                                      \
        for (int qs = 0; qs < 2; ++qs) {                                       \
            float rm = rmax[qs];                                               \
            rm = fmaxf(rm, __shfl_xor(rm, 16));                                \
            rm = fmaxf(rm, __shfl_xor(rm, 32));                                \
            const float newm = fmaxf(m_[qs], rm);                              \
            const float fac = exp2f_fast(m_[qs] - newm);                       \
            m_[qs] = newm;                                                     \
            float facq[4];                                                     \
            _Pragma("unroll")                                                  \
            for (int jj = 0; jj < 4; ++jj)                                     \
                facq[jj] = __shfl(fac, lg * 4 + jj);                           \
            _Pragma("unroll")                                                  \
            for (int t = 0; t < 5; ++t)                                        \
                _Pragma("unroll")                                              \
                for (int jj = 0; jj < 4; ++jj)                                 \
                    o[qs][t][jj] *= facq[jj];                                  \
        }                                                                      \
    }                                                                          \
    _Pragma("unroll")                                                          \
    for (int qs = 0; qs < 2; ++qs) {                                           \
        const int prow = qs * 64 + wave * 16 + l15;                            \
        const int pb64 = prow * 16;                                            \
        const int sw1 = (prow & 7) << 1;                                       \
        _Pragma("unroll")                                                      \
        for (int t = 0; t < 4; ++t) {                                          \
            const float p0 = exp2f_fast(S[qs][t][0] - m_[qs]);                 \
            const float p1 = exp2f_fast(S[qs][t][1] - m_[qs]);                 \
            const float p2 = exp2f_fast(S[qs][t][2] - m_[qs]);                 \
            const float p3 = exp2f_fast(S[qs][t][3] - m_[qs]);                 \
            const uint32_t lo = cvtpk_bf16(p0, p1);                            \
            const uint32_t hi = cvtpk_bf16(p2, p3);                            \
            Ps64[pb64 + ((t * 4 + lg) ^ sw1)] =                                \
                (unsigned long long)lo | ((unsigned long long)hi << 32);       \
        }                                                                      \
    }                                                                          \
    __builtin_amdgcn_s_setprio(1);                                             \
    _Pragma("unroll")                                                          \
    for (int ks = 0; ks < 2; ++ks) {                                           \
        const int kb2 = ks * 32 + lg * 8;                                      \
        const int pr0 = wave * 16 + l15;                                       \
        const int pr1 = 64 + pr0;                                              \
        const short8 ap0 = *reinterpret_cast<const short8*>(                   \
            &Ps[pr0 * 64 + (kb2 ^ ((pr0 & 7) << 3))]);                         \
        const short8 ap1 = *reinterpret_cast<const short8*>(                   \
            &Ps[pr1 * 64 + (kb2 ^ ((pr1 & 7) << 3))]);                         \
        _Pragma("unroll")                                                      \
        for (int t = 0; t < 4; ++t) {                                          \
            const int dr = t * 16 + l15;                                       \
            const short8 bv = *reinterpret_cast<const short8*>(                \
                &(VBUF)[dr * 64 + (kb2 ^ ((dr & 7) << 3))]);                   \
            o[0][t] = __builtin_amdgcn_mfma_f32_16x16x32_bf16(                 \
                ap0, bv, o[0][t], 0, 0, 0);                                    \
            o[1][t] = __builtin_amdgcn_mfma_f32_16x16x32_bf16(                 \
                ap1, bv, o[1][t], 0, 0, 0);                                    \
        }                                                                      \
        o[0][4] = __builtin_amdgcn_mfma_f32_16x16x32_bf16(                     \
            ap0, ones, o[0][4], 0, 0, 0);                                      \
        o[1][4] = __builtin_amdgcn_mfma_f32_16x16x32_bf16(                     \
            ap1, ones, o[1][4], 0, 0, 0);                                      \
    }                                                                          \
    __builtin_amdgcn_s_setprio(0);                                             \
} while (0)

    // prologue: K(0),K(1),V(0) staged; score tile 0
    STAGE_K(0, kb0);
    STAGE_K(1, kb1);
    STAGE_V(0, vb0);
    __syncthreads();
    QK_STEP(SA, kb0);

    // half-iters t=0..29 (unroll 2: even uses kb0/vb0 for tile t, odd kb1/vb1)
    #pragma unroll 1
    for (int t2 = 0; t2 < 30; t2 += 2) {
        // t even
        __syncthreads();
        STAGE_K(t2 + 2, kb0);
        STAGE_V(t2 + 1, vb1);
        QK_STEP(SB, kb1);          // tile t+1
        SMPV_STEP(SA, vb0);        // tile t
        // t odd
        __syncthreads();
        STAGE_K(t2 + 3, kb1);
        STAGE_V(t2 + 2, vb0);
        QK_STEP(SA, kb0);          // tile t+2
        SMPV_STEP(SB, vb1);        // tile t+1
    }
    // t = 30 (even): QK(31), SMPV(30); stage only V(31)
    __syncthreads();
    STAGE_V(31, vb1);
    QK_STEP(SB, kb1);
    SMPV_STEP(SA, vb0);
    // t = 31 (odd): SMPV(31)
    __syncthreads();
    SMPV_STEP(SB, vb1);

#undef STAGE_K
#undef STAGE_V
#undef QK_STEP
#undef SMPV_STEP

    #pragma unroll
    for (int qs = 0; qs < 2; ++qs)
        #pragma unroll
        for (int jj = 0; jj < 4; ++jj) {
            const float inv = 1.0f / o[qs][4][jj];
            const size_t row = (size_t)b * N_ + qt * 128 + qs * 64 + wave * 16 + lg * 4 + jj;
            #pragma unroll
            for (int t = 0; t < 4; ++t)
                att[row * (2 * DK_) + h * HK_ + t * 16 + l15] =
                    f2bf_fast(o[qs][t][jj] * inv);
        }
}

// sum partials, softmax over qd, write distfT[bh][qd][kd] bf16.
// Grid (32, 4): bh x 16-kd-row groups.
__global__ __launch_bounds__(256) void featSM_kernel(
    const float* __restrict__ partials, u16* __restrict__ distfT)
{
    const int bh = blockIdx.x, rg = blockIdx.y, tid = threadIdx.x;
    const int r = rg * 16 + (tid >> 4);   // kd row
    const int tl = tid & 15;              // qd group: qd = tl*4 .. +3
    float v[4] = {0.0f, 0.0f, 0.0f, 0.0f};
    for (int s = 0; s < 8; ++s) {
        const float4 a = *reinterpret_cast<const float4*>(
            &partials[(((size_t)s * 32 + bh) * 64 + r) * 64 + tl * 4]);
        v[0] += a.x; v[1] += a.y; v[2] += a.z; v[3] += a.w;
    }
    float m = fmaxf(fmaxf(v[0], v[1]), fmaxf(v[2], v[3]));
    m = fmaxf(m, __shfl_xor(m, 1));
    m = fmaxf(m, __shfl_xor(m, 2));
    m = fmaxf(m, __shfl_xor(m, 4));
    m = fmaxf(m, __shfl_xor(m, 8));
    float sum = 0.0f;
    #pragma unroll
    for (int j = 0; j < 4; ++j) { v[j] = exp2f_fast(v[j] - m); sum += v[j]; }
    sum += __shfl_xor(sum, 1);
    sum += __shfl_xor(sum, 2);
    sum += __shfl_xor(sum, 4);
    sum += __shfl_xor(sum, 8);
    const float inv = 1.0f / sum;
    #pragma unroll
    for (int j = 0; j < 4; ++j)
        distfT[(size_t)bh * 4096 + (tl * 4 + j) * 64 + r] = f2bf_fast(v[j] * inv);
}

// att_f[n,q] = sum_d V[n,d] * distf[d,q] -> att[:, 512+h*64+q] (MFMA).
// Grid (32, NH, B): one 64-row chunk per block.
__global__ __launch_bounds__(256) void featAV_mfma(
    const u16* __restrict__ V, const u16* __restrict__ distfT,
    u16* __restrict__ att)
{
    __shared__ u16 Bs[64 * 64];   // distfT[q][d], XOR-swizzled
    __shared__ u16 As[64 * 64];   // V rows
    const int tid = threadIdx.x;
    const int lane = tid & 63, wave = tid >> 6;
    const int l15 = lane & 15, lg = lane >> 4;
    const int ns = blockIdx.x, h = blockIdx.y, b = blockIdx.z;
    const int bh = b * NH_ + h;
    const int n0 = ns * 64;

    #pragma unroll
    for (int it = 0; it < 2; ++it) {
        const int idx = tid + it * 256;
        const int r = idx >> 3, c0 = (idx & 7) * 8;
        const u16x8 dv = *reinterpret_cast<const u16x8*>(
            &distfT[(size_t)bh * 4096 + r * 64 + c0]);
        *reinterpret_cast<u16x8*>(&Bs[r * 64 + (c0 ^ ((r & 7) << 3))]) = dv;
    }
    #pragma unroll
    for (int i = 0; i < 2; ++i) {
        const int ob = (wave * 2 + i) * 1024;
        const int o_ = ob + lane * 16;
        const int row = o_ >> 7;
        const int inner = (o_ & 127) ^ ((row & 7) << 4);
        gload16((const char*)V + ((size_t)(b * N_ + n0 + row) * DK_ + h * HK_) * 2 + inner,
                (char*)As + ob);
    }
    __syncthreads();
    f32x4 acc[4] = {};
    #pragma unroll
    for (int ks = 0; ks < 2; ++ks) {
        const int kb2 = ks * 32 + lg * 8;
        const int ar = wave * 16 + l15;
        const short8 av = *reinterpret_cast<const short8*>(
            &As[ar * 64 + (kb2 ^ ((ar & 7) << 3))]);
        #pragma unroll
        for (int ni = 0; ni < 4; ++ni) {
            const int br = ni * 16 + l15;
            const short8 bd = *reinterpret_cast<const short8*>(
                &Bs[br * 64 + (kb2 ^ ((br & 7) << 3))]);
            acc[ni] = __builtin_amdgcn_mfma_f32_16x16x32_bf16(av, bd, acc[ni], 0, 0, 0);
        }
    }
    #pragma unroll
    for (int ni = 0; ni < 4; ++ni)
        #pragma unroll
        for (int jj = 0; jj < 4; ++jj)
            att[((size_t)b * N_ + n0 + wave * 16 + lg * 4 + jj) * (2 * DK_)
                + 512 + h * HK_ + ni * 16 + l15] = f2bf_fast(acc[ni][jj]);
}

// ---------------------------------------------------------------------------
// LayerNorm, wave-per-row: grid 2048 x 256 thr (4 waves = 4 rows/block).
// ---------------------------------------------------------------------------
__global__ __launch_bounds__(256) void ln_kernel(
    const u16* __restrict__ fc, const float* __restrict__ gamma,
    const float* __restrict__ beta, float* __restrict__ out)
{
    const int row = blockIdx.x * 4 + (threadIdx.x >> 6);
    const int lane = threadIdx.x & 63;
    const int c = lane * 8;
    const u16x8 v = *reinterpret_cast<const u16x8*>(&fc[(size_t)row * D_ + c]);
    float f[8];
    float s = 0.0f, sq = 0.0f;
    #pragma unroll
    for (int j = 0; j < 8; ++j) {
        f[j] = b2f(v[j]);
        s += f[j];
        sq = fmaf(f[j], f[j], sq);
    }
    #pragma unroll
    for (int off = 32; off >= 1; off >>= 1) {
        s  += __shfl_xor(s, off);
        sq += __shfl_xor(sq, off);
    }
    const float mu = s * (1.0f / D_);
    const float var = sq * (1.0f / D_) - mu * mu;
    const float rstd = rsqrtf(var + LN_EPS_);
    const float4 g0 = *reinterpret_cast<const float4*>(&gamma[c]);
    const float4 g1 = *reinterpret_cast<const float4*>(&gamma[c + 4]);
    const float4 b0 = *reinterpret_cast<const float4*>(&beta[c]);
    const float4 b1 = *reinterpret_cast<const float4*>(&beta[c + 4]);
    const float gg[8] = {g0.x, g0.y, g0.z, g0.w, g1.x, g1.y, g1.z, g1.w};
    const float bb[8] = {b0.x, b0.y, b0.z, b0.w, b1.x, b1.y, b1.z, b1.w};
    float4 o0, o1;
    o0.x = (f[0] - mu) * rstd * gg[0] + bb[0];
    o0.y = (f[1] - mu) * rstd * gg[1] + bb[1];
    o0.z = (f[2] - mu) * rstd * gg[2] + bb[2];
    o0.w = (f[3] - mu) * rstd * gg[3] + bb[3];
    o1.x = (f[4] - mu) * rstd * gg[4] + bb[4];
    o1.y = (f[5] - mu) * rstd * gg[5] + bb[5];
    o1.z = (f[6] - mu) * rstd * gg[6] + bb[6];
    o1.w = (f[7] - mu) * rstd * gg[7] + bb[7];
    *reinterpret_cast<float4*>(&out[(size_t)row * D_ + c]) = o0;
    *reinterpret_cast<float4*>(&out[(size_t)row * D_ + c + 4]) = o1;
}

// ---------------------------------------------------------------------------
extern "C" void kernel_launch(void* const* d_in, const int* in_sizes, int n_in,
                              void* d_out, int out_size, void* d_ws, size_t ws_size,
                              hipStream_t stream)
{
    (void)in_sizes; (void)n_in; (void)out_size; (void)ws_size;
    const float* x     = (const float*)d_in[0];
    const float* Wq    = (const float*)d_in[1];
    const float* Wk    = (const float*)d_in[2];
    const float* Wv    = (const float*)d_in[3];
    const float* Wf    = (const float*)d_in[4];
    const float* bf    = (const float*)d_in[5];
    const float* gamma = (const float*)d_in[6];
    const float* beta  = (const float*)d_in[7];
    float* out = (float*)d_out;

    char* w = (char*)d_ws;
    const size_t SZE = (size_t)B_ * N_ * DK_;            // 4,194,304 elems
    u16* xb     = (u16*)w;   w += SZE * 2;
    u16* wqkvT  = (u16*)w;   w += (size_t)1536 * 512 * 2;
    u16* wfT    = (u16*)w;   w += (size_t)512 * 1024 * 2;
    u16* qb     = (u16*)w;   w += SZE * 2;
    u16* kb     = (u16*)w;   w += SZE * 2;
    u16* vb     = (u16*)w;   w += SZE * 2;
    u16* vt     = (u16*)w;   w += SZE * 2;
    u16* attb   = (u16*)w;   w += SZE * 2 * 2;
    float* partials = (float*)w; w += (size_t)8 * 32 * 4096 * 4;   // 4 MB
    u16* distfT = (u16*)w;   w += (size_t)32 * 4096 * 2;
    u16* fcout  = (u16*)w;   // 8192*512*2 = 8.4 MB

    const dim3 blk(256);

    // merged prep: x->bf16 + 4 weight transposes (1 launch)
    prep_kernel<<<dim3(3328), blk, 0, stream>>>(x, Wq, Wk, Wv, Wf, xb, wqkvT, wfT);

    // fused QKV projection (2-phase pipelined, 64x128 tile): q pre-scaled,
    // v dual-written
    gemm_qkv_kernel<<<dim3(1536), blk, 0, stream>>>(xb, wqkvT, qb, kb, vb, vt);

    // FAT launch: flash (512 blocks, QK-ahead pipeline) + featS (256 blocks)
    flash_featS_kernel<<<dim3(768), blk, 0, stream>>>(qb, kb, vt, attb, partials);

    featSM_kernel<<<dim3(32, 4), blk, 0, stream>>>(partials, distfT);
    featAV_mfma<<<dim3(32, NH_, B_), blk, 0, stream>>>(vb, distfT, attb);

    // FC + bias + relu + resid -> bf16 fcout (2-phase pipelined)
    gemm_fc_kernel<<<dim3(512), blk, 0, stream>>>(attb, wfT, fcout, bf, x);

    // LayerNorm (wave-per-row)
    ln_kernel<<<dim3(2048), blk, 0, stream>>>(fcout, gamma, beta, out);
}